// Round 2
// baseline (3622.071 us; speedup 1.0000x reference)
//
#include <hip/hip_runtime.h>

typedef unsigned short u16;
typedef __attribute__((ext_vector_type(8))) short short8;
typedef __attribute__((ext_vector_type(4))) float f32x4;

union U16x8 { uint4 u; short8 s; u16 h[8]; };

__device__ __forceinline__ float b2f(u16 u) {
  union { unsigned int i; float f; } x; x.i = ((unsigned int)u) << 16; return x.f;
}
__device__ __forceinline__ u16 f2b(float f) {
  union { float f; unsigned int i; } x; x.f = f;
  unsigned int r = x.i + 0x7FFFu + ((x.i >> 16) & 1u);
  return (u16)(r >> 16);
}
__device__ __forceinline__ float sig_(float x) { return 1.0f / (1.0f + __expf(-x)); }
__device__ __forceinline__ float tanh_(float x) {
  float e = __expf(2.0f * x);
  return 1.0f - 2.0f / (e + 1.0f);
}

#define BS_ 16640L  // 65*256, per-batch stride of buf_s

// ---------- convert reused weights fp32 -> bf16 into ws ----------
__global__ __launch_bounds__(256) void kprep(
    const float* __restrict__ a0, const float* __restrict__ a1,
    const float* __restrict__ a2, const float* __restrict__ a3,
    const float* __restrict__ a4, const float* __restrict__ a5,
    u16* __restrict__ dst)
{
  int i = blockIdx.x * 256 + threadIdx.x;
  const float* s; int o;
  if (i < 65536)        { s = a0; o = i; }
  else if (i < 851968)  { s = a1; o = i - 65536; }
  else if (i < 1114112) { s = a2; o = i - 851968; }
  else if (i < 1441792) { s = a3; o = i - 1114112; }
  else if (i < 1769472) { s = a4; o = i - 1441792; }
  else                  { s = a5; o = i - 1769472; }
  dst[i] = f2b(s[o]);
}

// ---------- init: zero tc, th[0], head logits ----------
__global__ __launch_bounds__(256) void kinit(float* tc, u16* thb, float* lg1) {
  int i = blockIdx.x * 256 + threadIdx.x;
  if (i < 262144) { tc[i] = 0.0f; thb[i] = 0; }
  if (i < 193536) lg1[i] = 0.0f;
}

// ---------- phase 1: buf = selu(embed[tok] @ W_in^T + b), outputs0 head ----------
__global__ __launch_bounds__(256) void kbuf(
    const int* __restrict__ tokens, const float* __restrict__ embed,
    const u16* __restrict__ w_inB, const float* __restrict__ b_in,
    const float* __restrict__ w_out, const float* __restrict__ b_out,
    float* __restrict__ out0, u16* __restrict__ buf_s, u16* __restrict__ padv)
{
  __shared__ u16 Wl[256 * 264];
  __shared__ u16 Xl[16 * 264];
  __shared__ u16 Bufl[16 * 264];
  __shared__ int posb[16], post[16];
  const int tid = threadIdx.x;
  {
    const uint4* s = (const uint4*)(w_inB + tid * 256);
    uint4* d = (uint4*)(Wl + tid * 264);
#pragma unroll 8
    for (int i = 0; i < 32; ++i) d[i] = s[i];
  }
  const int pos0 = blockIdx.x * 16;
  if (tid < 16) {
    int pos = pos0 + tid;
    int b = pos / 127;
    posb[tid] = b; post[tid] = pos - b * 127;
  }
  {
    int p = tid >> 4, t16 = tid & 15;
    int pos = pos0 + p;
    int b = pos / 127;
    int t = pos - b * 127;
    int tok = tokens[b * 127 + t];
    const float4* s = (const float4*)(embed + (size_t)tok * 256 + t16 * 16);
#pragma unroll
    for (int j = 0; j < 4; ++j) {
      float4 v = s[j];
      u16* d = Xl + p * 264 + t16 * 16 + j * 4;
      d[0] = f2b(v.x); d[1] = f2b(v.y); d[2] = f2b(v.z); d[3] = f2b(v.w);
    }
  }
  __syncthreads();

  float acc[16];
#pragma unroll
  for (int p = 0; p < 16; ++p) acc[p] = 0.0f;
#pragma unroll 4
  for (int e = 0; e < 256; e += 8) {
    U16x8 wv; wv.u = *(const uint4*)(Wl + tid * 264 + e);
    float wf[8];
#pragma unroll
    for (int j = 0; j < 8; ++j) wf[j] = b2f(wv.h[j]);
#pragma unroll
    for (int p = 0; p < 16; ++p) {
      U16x8 xv; xv.u = *(const uint4*)(Xl + p * 264 + e);
      float s = acc[p];
#pragma unroll
      for (int j = 0; j < 8; ++j) s += wf[j] * b2f(xv.h[j]);
      acc[p] = s;
    }
  }
  float bi = b_in[tid];
  const float SELU_A = 1.6732632423543772f, SELU_S = 1.0507009873554805f;
#pragma unroll
  for (int p = 0; p < 16; ++p) {
    float v = acc[p] + bi;
    v = (v > 0.0f) ? SELU_S * v : SELU_S * SELU_A * (__expf(v) - 1.0f);
    acc[p] = v;
    Bufl[p * 264 + tid] = f2b(v);
  }
#pragma unroll 1
  for (int p = 0; p < 16; ++p) {
    int t = post[p], b = posb[p];
    if (t <= 64) buf_s[(size_t)b * BS_ + t * 256 + tid] = f2b(acc[p]);
    else if (t == 126 && b == 0) padv[tid] = f2b(acc[p]);
  }
  __syncthreads();
  {
    int w = tid >> 6, ln = tid & 63;
    for (int pp = 0; pp < 4; ++pp) {
      int p = w * 4 + pp;
      uint2 hu = *(const uint2*)(Bufl + p * 264 + ln * 4);
      const u16* hh = (const u16*)&hu;
      float lg[3];
#pragma unroll
      for (int o = 0; o < 3; ++o) {
        float4 wv = *(const float4*)(w_out + o * 256 + ln * 4);
        lg[o] = b2f(hh[0]) * wv.x + b2f(hh[1]) * wv.y + b2f(hh[2]) * wv.z + b2f(hh[3]) * wv.w;
      }
#pragma unroll
      for (int o = 0; o < 3; ++o)
        for (int off = 32; off > 0; off >>= 1) lg[o] += __shfl_down(lg[o], off);
      if (ln == 0) {
        float l0 = lg[0] + b_out[0];
        float l1 = lg[1] + b_out[1];
        float l2 = lg[2] + b_out[2];
        float m = fmaxf(l0, fmaxf(l1, l2));
        float lse = m + __logf(__expf(l0 - m) + __expf(l1 - m) + __expf(l2 - m));
        int t = post[p], b = posb[p];
        size_t o0 = ((size_t)t * 1024 + b) * 3;
        out0[o0 + 0] = l0 - lse;
        out0[o0 + 1] = l1 - lse;
        out0[o0 + 2] = l2 - lse;
      }
    }
  }
}

// ---------- tracker LSTM step ----------
__global__ __launch_bounds__(256) void ktrk(
    const u16* __restrict__ a0, long s0,
    const u16* __restrict__ a1, long s1,
    const u16* __restrict__ a2, long s2,
    const u16* __restrict__ a3,
    const u16* __restrict__ w_ihB, const u16* __restrict__ w_hhB,
    const float* __restrict__ b_ih, const float* __restrict__ b_hh,
    float* __restrict__ tc, u16* __restrict__ th_out)
{
  __shared__ u16 Bl[64 * 1048];
  const int tid = threadIdx.x;
  const int mblk = blockIdx.x, ns = blockIdx.y;
  {
    int col = tid >> 2, kseg = (tid & 3) * 256;
    int n = (col >> 4) * 256 + ns * 16 + (col & 15);
    const uint4* s = (const uint4*)((kseg < 768) ? (w_ihB + (size_t)n * 768 + kseg)
                                                 : (w_hhB + (size_t)n * 256));
    uint4* d = (uint4*)(Bl + col * 1048 + kseg);
#pragma unroll 8
    for (int i = 0; i < 32; ++i) d[i] = s[i];
  }
  __syncthreads();
  const int wv = tid >> 6, ln = tid & 63;
  const int l15 = ln & 15, lq = ln >> 4;
  const long grow = mblk * 64 + wv * 16 + l15;
  const u16* ap[4] = { a0 + grow * s0, a1 + grow * s1, a2 + grow * s2, a3 + grow * 256 };
  f32x4 acc[4] = { {0.f,0.f,0.f,0.f}, {0.f,0.f,0.f,0.f}, {0.f,0.f,0.f,0.f}, {0.f,0.f,0.f,0.f} };
#pragma unroll 1
  for (int ch = 0; ch < 4; ++ch) {
    const u16* a = ap[ch] + 8 * lq;
#pragma unroll
    for (int kk = 0; kk < 8; ++kk) {
      U16x8 av; av.u = *(const uint4*)(a + kk * 32);
#pragma unroll
      for (int qt = 0; qt < 4; ++qt) {
        U16x8 bv; bv.u = *(const uint4*)(Bl + (qt * 16 + l15) * 1048 + ch * 256 + kk * 32 + 8 * lq);
        acc[qt] = __builtin_amdgcn_mfma_f32_16x16x32_bf16(av.s, bv.s, acc[qt], 0, 0, 0);
      }
    }
  }
  const int c = ns * 16 + l15;
  float bsum[4];
#pragma unroll
  for (int q = 0; q < 4; ++q) bsum[q] = b_ih[q * 256 + c] + b_hh[q * 256 + c];
#pragma unroll
  for (int i = 0; i < 4; ++i) {
    int row = mblk * 64 + wv * 16 + lq * 4 + i;
    size_t idx = (size_t)row * 256 + c;
    float gi = acc[0][i] + bsum[0];
    float gf = acc[1][i] + bsum[1];
    float gg = acc[2][i] + bsum[2];
    float go = acc[3][i] + bsum[3];
    float tcn = sig_(gf) * tc[idx] + sig_(gi) * tanh_(gg);
    tc[idx] = tcn;
    th_out[idx] = f2b(sig_(go) * tanh_(tcn));
  }
}

// ---------- reduce (TreeLSTM compose) + fused head-logit partials ----------
__global__ __launch_bounds__(256) void kred(
    const u16* __restrict__ lH, long lHs,
    const u16* __restrict__ rH, long rHs,
    const u16* __restrict__ thb,
    const void* __restrict__ lC, long lCs, int lCbf,
    const void* __restrict__ rC, long rCs, int rCbf,
    const u16* __restrict__ w_lB, const u16* __restrict__ w_rB,
    const u16* __restrict__ w_tB, const float* __restrict__ b_l,
    const float* __restrict__ w_out,
    u16* __restrict__ oH, float* __restrict__ oC, float* __restrict__ lgout)
{
  __shared__ u16 Bl[80 * 792];
  const int tid = threadIdx.x;
  const int mblk = blockIdx.x, ns = blockIdx.y;
  if (tid < 240) {
    int col = tid / 3, seg = tid % 3;
    int n = (col / 16) * 256 + ns * 16 + (col & 15);
    const u16* src = (seg == 0 ? w_lB : (seg == 1 ? w_rB : w_tB)) + (size_t)n * 256;
    const uint4* s = (const uint4*)src;
    uint4* d = (uint4*)(Bl + col * 792 + seg * 256);
#pragma unroll 8
    for (int i = 0; i < 32; ++i) d[i] = s[i];
  }
  __syncthreads();
  const int wv = tid >> 6, ln = tid & 63;
  const int l15 = ln & 15, lq = ln >> 4;
  const long grow = mblk * 64 + wv * 16 + l15;
  const u16* ap[3] = { lH + grow * lHs, rH + grow * rHs, thb + grow * 256 };
  f32x4 acc[5] = { {0.f,0.f,0.f,0.f}, {0.f,0.f,0.f,0.f}, {0.f,0.f,0.f,0.f},
                   {0.f,0.f,0.f,0.f}, {0.f,0.f,0.f,0.f} };
#pragma unroll 1
  for (int ch = 0; ch < 3; ++ch) {
    const u16* a = ap[ch] + 8 * lq;
#pragma unroll
    for (int kk = 0; kk < 8; ++kk) {
      U16x8 av; av.u = *(const uint4*)(a + kk * 32);
#pragma unroll
      for (int ct = 0; ct < 5; ++ct) {
        U16x8 bv; bv.u = *(const uint4*)(Bl + (ct * 16 + l15) * 792 + ch * 256 + kk * 32 + 8 * lq);
        acc[ct] = __builtin_amdgcn_mfma_f32_16x16x32_bf16(av.s, bv.s, acc[ct], 0, 0, 0);
      }
    }
  }
  const int c = ns * 16 + l15;
  float hv[4];
#pragma unroll
  for (int i = 0; i < 4; ++i) {
    int row = mblk * 64 + wv * 16 + lq * 4 + i;
    size_t idx = (size_t)row * 256 + c;
    float a_ = acc[0][i] + b_l[c];
    float ig = acc[1][i] + b_l[256 + c];
    float f1 = acc[2][i] + b_l[512 + c];
    float f2 = acc[3][i] + b_l[768 + c];
    float og = acc[4][i] + b_l[1024 + c];
    float lc = lCbf ? b2f(((const u16*)lC)[row * lCs + c]) : ((const float*)lC)[row * lCs + c];
    float rc = rCbf ? b2f(((const u16*)rC)[row * rCs + c]) : ((const float*)rC)[row * rCs + c];
    float cn = tanh_(a_) * sig_(ig) + sig_(f1) * lc + sig_(f2) * rc;
    float hn = sig_(og) * tanh_(cn);
    oH[idx] = f2b(hn);
    oC[idx] = cn;
    hv[i] = hn;
  }
  // fused head: partial dot h . w_out over this block's 16 cols, reduce over l15 group
  float wo[3] = { w_out[c], w_out[256 + c], w_out[512 + c] };
  float pr[12];
#pragma unroll
  for (int o = 0; o < 3; ++o)
#pragma unroll
    for (int i = 0; i < 4; ++i) pr[o * 4 + i] = hv[i] * wo[o];
#pragma unroll
  for (int u = 0; u < 12; ++u)
#pragma unroll
    for (int m = 1; m < 16; m <<= 1) pr[u] += __shfl_xor(pr[u], m);
  if (l15 == 0) {
    int rb = mblk * 64 + wv * 16 + lq * 4;
#pragma unroll
    for (int o = 0; o < 3; ++o)
#pragma unroll
      for (int i = 0; i < 4; ++i)
        atomicAdd(lgout + (size_t)(rb + i) * 3 + o, pr[o * 4 + i]);
  }
}

// ---------- finalize outs1: log-softmax of accumulated logits ----------
__global__ __launch_bounds__(256) void kfin(const float* __restrict__ lg1,
    const float* __restrict__ b_out, float* __restrict__ out1)
{
  int r = blockIdx.x * 256 + threadIdx.x;
  if (r >= 64512) return;
  float l0 = lg1[r * 3 + 0] + b_out[0];
  float l1 = lg1[r * 3 + 1] + b_out[1];
  float l2 = lg1[r * 3 + 2] + b_out[2];
  float m = fmaxf(l0, fmaxf(l1, l2));
  float lse = m + __logf(__expf(l0 - m) + __expf(l1 - m) + __expf(l2 - m));
  out1[r * 3 + 0] = l0 - lse;
  out1[r * 3 + 1] = l1 - lse;
  out1[r * 3 + 2] = l2 - lse;
}

extern "C" void kernel_launch(void* const* d_in, const int* in_sizes, int n_in,
                              void* d_out, int out_size, void* d_ws, size_t ws_size,
                              hipStream_t stream) {
  const int* tokens   = (const int*)d_in[0];
  const float* embed  = (const float*)d_in[2];
  const float* w_in   = (const float*)d_in[3];
  const float* b_in   = (const float*)d_in[4];
  const float* left_w = (const float*)d_in[5];
  const float* left_b = (const float*)d_in[6];
  const float* right_w= (const float*)d_in[7];
  const float* track_w= (const float*)d_in[8];
  const float* w_ih   = (const float*)d_in[9];
  const float* w_hh   = (const float*)d_in[10];
  const float* b_ih   = (const float*)d_in[11];
  const float* b_hh   = (const float*)d_in[12];
  const float* w_out  = (const float*)d_in[13];
  const float* b_out  = (const float*)d_in[14];
  float* out = (float*)d_out;

  char* ws = (char*)d_ws;
  u16* wB    = (u16*)ws;                    // bf16 weight pool, 2,097,152 el
  u16* w_inB = wB;
  u16* w_ihB = wB + 65536;
  u16* w_hhB = wB + 851968;
  u16* w_lB  = wB + 1114112;
  u16* w_rB  = wB + 1441792;
  u16* w_tB  = wB + 1769472;
  u16* buf_s = (u16*)(ws + 4194304);        // [1024][65][256] bf16
  u16* padv  = (u16*)(ws + 38273024);       // [256] bf16
  u16* hR    = (u16*)(ws + 38273536);       // [2][1024][256] bf16
  float* rCb = (float*)(ws + 39322112);     // [2][1024][256] f32
  float* tcb = (float*)(ws + 41419264);     // [1024][256] f32
  u16* thb   = (u16*)(ws + 42467840);       // [2][1024][256] bf16
  float* lg1 = (float*)(ws + 43516416);     // [63][1024][3] f32

  kprep<<<8192, 256, 0, stream>>>(w_in, w_ih, w_hh, left_w, right_w, track_w, wB);
  kinit<<<1024, 256, 0, stream>>>(tcb, thb, lg1);
  kbuf<<<8128, 256, 0, stream>>>(tokens, embed, w_inB, b_in, w_out, b_out, out, buf_s, padv);

  auto Bp = [&](int j) { return buf_s + j * 256; };
  auto Hp = [&](int i) { return hR + (size_t)(i & 1) * 262144; };
  auto Cp = [&](int i) { return rCb + (size_t)(i & 1) * 262144; };

  dim3 g(16, 16), blk(256, 1, 1);
  for (int t = 0; t < 127; ++t) {
    const u16 *A1, *A2; long S1, S2;
    int k; bool isR = false;
    if (t == 0)      { k = 0;  A1 = padv;  S1 = 0;   A2 = padv;  S2 = 0;   }
    else if (t == 1) { k = 1;  A1 = Bp(0); S1 = BS_; A2 = padv;  S2 = 0;   }
    else if (t == 2) { k = 2;  A1 = Bp(1); S1 = BS_; A2 = Bp(0); S2 = BS_; }
    else if (t == 3) { k = 3;  A1 = Bp(2); S1 = BS_; A2 = Bp(1); S2 = BS_; isR = true; }
    else if (t == 126) { k = 64; A1 = Hp(62); S1 = 256; A2 = Bp(0); S2 = BS_; isR = true; }
    else if ((t & 1) == 0) { int i = (t - 2) / 2; k = i + 2; A1 = Hp(i); S1 = 256; A2 = Bp(0); S2 = BS_; }
    else { int i = (t - 3) / 2; k = i + 3; A1 = Bp(i + 2); S1 = BS_; A2 = Hp(i); S2 = 256; isR = true; }

    ktrk<<<g, blk, 0, stream>>>(Bp(k), BS_, A1, S1, A2, S2, thb + (t & 1) * 262144,
                                w_ihB, w_hhB, b_ih, b_hh, tcb,
                                thb + ((t + 1) & 1) * 262144);
    if (isR) {
      const u16 *lHp, *rHp; long lHs, rHs;
      const void *lCp, *rCp; long lCs, rCs; int lbf, rbf, j;
      if (t == 3) {
        j = 1;
        lHp = Bp(1); lHs = BS_; lCp = Bp(1); lCs = BS_; lbf = 1;
        rHp = Bp(2); rHs = BS_; rCp = Bp(2); rCs = BS_; rbf = 1;
      } else if (t == 126) {
        j = 63;
        lHp = Bp(0); lHs = BS_; lCp = Bp(0); lCs = BS_; lbf = 1;
        rHp = Hp(62); rHs = 256; rCp = Cp(62); rCs = 256; rbf = 0;
      } else {
        int i = (t - 3) / 2; j = i + 1;
        lHp = Hp(i); lHs = 256; lCp = Cp(i); lCs = 256; lbf = 0;
        rHp = Bp(i + 2); rHs = BS_; rCp = Bp(i + 2); rCs = BS_; rbf = 1;
      }
      kred<<<g, blk, 0, stream>>>(lHp, lHs, rHp, rHs, thb + ((t + 1) & 1) * 262144,
                                  lCp, lCs, lbf, rCp, rCs, rbf,
                                  w_lB, w_rB, w_tB, left_b, w_out,
                                  Hp(j), Cp(j), lg1 + (size_t)(j - 1) * 3072);
    }
  }
  kfin<<<252, 256, 0, stream>>>(lg1, b_out, out + 390144);
}